// Round 1
// baseline (1000.524 us; speedup 1.0000x reference)
//
#include <hip/hip_runtime.h>
#include <cstdint>
#include <cstddef>

typedef __attribute__((ext_vector_type(8))) short short8;       // 8 x bf16 bits (MFMA A/B frag)
typedef __attribute__((ext_vector_type(4))) float floatx4;      // MFMA C/D frag
typedef __attribute__((ext_vector_type(4))) unsigned int uintx4;

#define DEV static __device__ __forceinline__

constexpr int NT = 2, NB = 16, NC = 256, NN = 4096, NHD = 8;
constexpr size_t NE1 = (size_t)NT * NB * NC * NN;   // elements per output tensor
constexpr size_t TSTRIDE = (size_t)NB * NC * NN;    // t-stride in elements

// ---------- helpers ----------
DEV unsigned short f2bf(float x) {            // round-to-nearest-even fp32 -> bf16 bits
  unsigned int u = __builtin_bit_cast(unsigned int, x);
  unsigned int lsb = (u >> 16) & 1u;
  u += 0x7FFFu + lsb;
  return (unsigned short)(u >> 16);
}
DEV float bfb2f(unsigned short h) {
  unsigned int u = ((unsigned int)h) << 16;
  return __builtin_bit_cast(float, u);
}
DEV unsigned int pk2(unsigned short a, unsigned short b) {
  return (unsigned int)a | ((unsigned int)b << 16);
}
// bank-conflict-free slot mapping for [rows][32 bf16] tiles: chunk kk (16B) of row fr
// lives at slot fr*4 + (kk ^ ((fr>>1)&3)).
DEV int swz(int fr, int kk) { return fr * 4 + (kk ^ ((fr >> 1) & 3)); }
// async global->LDS, 16B per lane; LDS dest is wave-uniform base + lane*16
typedef __attribute__((address_space(3))) unsigned int lds_u32;
typedef __attribute__((address_space(1))) const unsigned int glb_u32;
DEV void gld_lds16(const void* g, void* l) {
  __builtin_amdgcn_global_load_lds((glb_u32*)g, (lds_u32*)l, 16, 0, 0);
}
// B-unpack: 16 spike bits -> 16 bf16 (two 16B chunks) written to swizzled slots
DEV void stage_bits(unsigned int wb, int fr, int bhalf, unsigned short* Bdst) {
  uintx4 c0v, c1v;
  #pragma unroll
  for (int p = 0; p < 4; p++) {
    c0v[p] = pk2(((wb >> (2 * p)) & 1) ? 0x3F80 : 0, ((wb >> (2 * p + 1)) & 1) ? 0x3F80 : 0);
    c1v[p] = pk2(((wb >> (8 + 2 * p)) & 1) ? 0x3F80 : 0, ((wb >> (9 + 2 * p)) & 1) ? 0x3F80 : 0);
  }
  *(uintx4*)(Bdst + (size_t)swz(fr, bhalf * 2)     * 8) = c0v;
  *(uintx4*)(Bdst + (size_t)swz(fr, bhalf * 2 + 1) * 8) = c1v;
}

// ---------- kernel 1: weight split + BN constant prep ----------
__global__ __launch_bounds__(256) void prep_kernel(
    const float* __restrict__ wq, const float* __restrict__ wk, const float* __restrict__ wv,
    const float* __restrict__ wp, const float* __restrict__ bp,
    const float* __restrict__ qg, const float* __restrict__ qb, const float* __restrict__ qm, const float* __restrict__ qva,
    const float* __restrict__ kg, const float* __restrict__ kb, const float* __restrict__ km, const float* __restrict__ kva,
    const float* __restrict__ vg, const float* __restrict__ vb, const float* __restrict__ vm, const float* __restrict__ vva,
    const float* __restrict__ pg, const float* __restrict__ pb, const float* __restrict__ pm, const float* __restrict__ pva,
    unsigned short* __restrict__ Wqkv, unsigned short* __restrict__ Wp,
    float* __restrict__ invqkv, float* __restrict__ shqkv,
    float* __restrict__ invp, float* __restrict__ shp)
{
  int idx = blockIdx.x * 256 + threadIdx.x;
  if (idx < 196608) {                       // Wq|Wk|Wv stacked [768][256], 3-way bf16 split
    int o = idx >> 8, c = idx & 255;
    const float* src = (o < 256) ? wq : (o < 512) ? wk : wv;
    float w = src[(size_t)(o & 255) * 256 + c];
    unsigned short h0 = f2bf(w);  float f0 = bfb2f(h0);
    float r1 = w - f0;
    unsigned short h1 = f2bf(r1); float f1 = bfb2f(h1);
    float r2 = r1 - f1;
    unsigned short h2 = f2bf(r2);
    Wqkv[idx] = h0; Wqkv[196608 + idx] = h1; Wqkv[393216 + idx] = h2;
  } else if (idx < 262144) {                // Wp [256][256], 3-way split
    int j = idx - 196608;
    float w = wp[j];
    unsigned short h0 = f2bf(w);  float f0 = bfb2f(h0);
    float r1 = w - f0;
    unsigned short h1 = f2bf(r1); float f1 = bfb2f(h1);
    float r2 = r1 - f1;
    unsigned short h2 = f2bf(r2);
    Wp[j] = h0; Wp[65536 + j] = h1; Wp[131072 + j] = h2;
  } else if (idx < 262912) {                // BN constants for q,k,v stacked [768]
    int i = idx - 262144;
    int p = i >> 8, c = i & 255;
    float g  = (p == 0) ? qg[c] : (p == 1) ? kg[c] : vg[c];
    float be = (p == 0) ? qb[c] : (p == 1) ? kb[c] : vb[c];
    float mn = (p == 0) ? qm[c] : (p == 1) ? km[c] : vm[c];
    float vr = (p == 0) ? qva[c] : (p == 1) ? kva[c] : vva[c];
    float sq = sqrtf(vr + 1e-5f);
    invqkv[i] = g / sq;
    shqkv[i]  = be - (mn * g) / sq;
  } else if (idx < 263168) {                // BN constants for p, bias folded in
    int c = idx - 262912;
    float sq = sqrtf(pva[c] + 1e-5f);
    float iv = pg[c] / sq;
    invp[c] = iv;
    shp[c]  = pb[c] - (pm[c] * pg[c]) / sq + bp[c] * iv;
  }
}

// ---------- kernel 2: LIF on x -> xs (fp32 [t,b,c,n]) + bit-plane xbits [z][n][c-word] ----------
__global__ __launch_bounds__(256) void lifx_kernel(const float* __restrict__ x,
                                                   float* __restrict__ xs_out,
                                                   unsigned short* __restrict__ xb16)
{
  __shared__ float tile[2][64][65];
  const int nt = blockIdx.x, ct = blockIdx.y, b = blockIdx.z;
  const int tid = threadIdx.x;
  const int ci = tid >> 2, cq = tid & 3;
  const int n0 = nt * 64, c0 = ct * 64;
  const size_t rowbase = ((size_t)(b * NC + c0 + ci)) * NN + n0 + cq * 16;
  const float* px0 = x + rowbase;
  const float* px1 = x + rowbase + TSTRIDE;
  float* po0 = xs_out + rowbase;
  float* po1 = xs_out + rowbase + TSTRIDE;
  #pragma unroll
  for (int jj = 0; jj < 4; jj++) {
    floatx4 x0 = *(const floatx4*)(px0 + jj * 4);
    floatx4 x1 = *(const floatx4*)(px1 + jj * 4);
    floatx4 s0v, s1v;
    #pragma unroll
    for (int e = 0; e < 4; e++) {
      float v1 = x0[e] * 0.5f;                       // exact
      float s0 = (v1 >= 1.0f) ? 1.0f : 0.0f;
      float vr = v1 * (1.0f - s0);                   // exact (0 or v1)
      float v2 = vr + (x1[e] - vr) * 0.5f;           // same rounding as reference
      float s1 = (v2 >= 1.0f) ? 1.0f : 0.0f;
      s0v[e] = s0; s1v[e] = s1;
      tile[0][ci][cq * 16 + jj * 4 + e] = s0;
      tile[1][ci][cq * 16 + jj * 4 + e] = s1;
    }
    *(floatx4*)(po0 + jj * 4) = s0v;
    *(floatx4*)(po1 + jj * 4) = s1v;
  }
  __syncthreads();
  const int ni = tid >> 2, cg = tid & 3;   // thread owns row n0+ni, c-word (c0>>4)+cg
  #pragma unroll
  for (int t = 0; t < 2; t++) {
    unsigned int wbits = 0;
    #pragma unroll
    for (int j = 0; j < 16; j++)
      wbits |= (tile[t][cg * 16 + j][ni] != 0.f ? 1u : 0u) << j;
    xb16[((size_t)((t * NB + b) * NN) + n0 + ni) * 16 + (c0 >> 4) + cg] = (unsigned short)wbits;
  }
}

// ---------- kernel 3: fused QKV GEMM + BN + LIF -> fp32 spikes + bit-planes ----------
// 2-phase prefetch pipeline: double-buffered LDS (A 2x24576 B, B 2x8192 B = 64 KiB),
// next tile's global_load_lds + B-unpack issued BEFORE current tile's compute, ONE
// barrier per K-step.  MFMA operand values and per-accumulator instruction order are
// IDENTICAL to the previous version => bit-identical results.
__global__ __launch_bounds__(256, 2) void qkv_gemm(
    const unsigned short* __restrict__ xb16,  // [z][n][16 c-words] bit-plane
    const unsigned short* __restrict__ Wsp,   // [3 splits][768][256] bf16
    const float* __restrict__ invv, const float* __restrict__ shv,  // [768]
    float* __restrict__ dq, float* __restrict__ dk, float* __restrict__ dv,
    unsigned short* __restrict__ qbits, unsigned short* __restrict__ kbits,
    unsigned short* __restrict__ vbits)
{
  __shared__ __align__(16) unsigned char smem[65536];
  float* yl = (float*)smem;                              // [128][65] overlaid for exchange
  const int nt = blockIdx.x, mt = blockIdx.y, b = blockIdx.z;
  const int tid = threadIdx.x;
  const int lane = tid & 63, quad = lane >> 4, l16 = lane & 15;
  const int wave = tid >> 6;
  const int tw = wave >> 1, wm = (wave & 1) * 64;        // waves 0,1: t=0 ; waves 2,3: t=1
  floatx4 acc[4][4] = {};
  const int bt = tid >> 7, brow = (tid >> 1) & 63, bhalf = tid & 1;
  const int frB = bt * 64 + brow;

  // hoisted B bit-word preload: 32 B per thread covers all 8 K-steps
  const unsigned short* xrowbase = xb16 + ((size_t)((bt * NB + b) * NN) + nt * 64 + brow) * 16;
  uintx4 xw0 = *(const uintx4*)(xrowbase);
  uintx4 xw1 = *(const uintx4*)(xrowbase + 8);

  // prologue: stage K-step 0 into buffer 0
  {
    #pragma unroll
    for (int j = 0; j < 6; j++) {
      int ci = j * 256 + tid;
      int fr = ci >> 2;
      int kk = (ci & 3) ^ ((fr >> 1) & 3);
      int s = fr >> 7, row = fr & 127;
      const unsigned short* g = Wsp + (size_t)s * 196608 + (size_t)(mt * 128 + row) * 256 + 0 + kk * 8;
      gld_lds16(g, (unsigned short*)smem + (size_t)ci * 8);
    }
    unsigned int w32 = xw0[0];
    unsigned int wb = bhalf ? (w32 >> 16) : (w32 & 0xFFFFu);
    stage_bits(wb, frB, bhalf, (unsigned short*)(smem + 49152));
  }
  __syncthreads();

  #pragma unroll
  for (int it = 0; it < 8; ++it) {
    unsigned short* Ac = (unsigned short*)(smem + (it & 1) * 24576);
    unsigned short* Bc = (unsigned short*)(smem + 49152 + (it & 1) * 8192);
    if (it < 7) {                        // issue next tile's A loads EARLY (latency hides under MFMA)
      unsigned short* An = (unsigned short*)(smem + ((it + 1) & 1) * 24576);
      const int k0 = (it + 1) * 32;
      #pragma unroll
      for (int j = 0; j < 6; j++) {
        int ci = j * 256 + tid;
        int fr = ci >> 2;
        int kk = (ci & 3) ^ ((fr >> 1) & 3);
        int s = fr >> 7, row = fr & 127;
        const unsigned short* g = Wsp + (size_t)s * 196608 + (size_t)(mt * 128 + row) * 256 + k0 + kk * 8;
        gld_lds16(g, An + (size_t)ci * 8);
      }
    }
    __builtin_amdgcn_sched_barrier(0);   // keep staging issue ahead of compute

    short8 bfr[4];
    #pragma unroll
    for (int ni = 0; ni < 4; ni++) {
      int fr = tw * 64 + ni * 16 + l16;
      bfr[ni] = *(const short8*)(Bc + (size_t)swz(fr, quad) * 8);
    }
    if (it < 7) {                        // next tile's B unpack+write overlaps MFMA
      unsigned short* Bn = (unsigned short*)(smem + 49152 + (((it + 1) & 1)) * 8192);
      unsigned int w32 = ((it + 1) < 4) ? xw0[(it + 1) & 3] : xw1[(it + 1) & 3];
      unsigned int wb = bhalf ? (w32 >> 16) : (w32 & 0xFFFFu);
      stage_bits(wb, frB, bhalf, Bn);
    }
    #pragma unroll
    for (int mi = 0; mi < 4; mi++) {
      const int r0 = wm + mi * 16 + l16;
      short8 a0 = *(const short8*)(Ac + (size_t)swz(      r0, quad) * 8);
      short8 a1 = *(const short8*)(Ac + (size_t)swz(128 + r0, quad) * 8);
      short8 a2 = *(const short8*)(Ac + (size_t)swz(256 + r0, quad) * 8);
      #pragma unroll
      for (int ni = 0; ni < 4; ni++) {
        acc[mi][ni] = __builtin_amdgcn_mfma_f32_16x16x32_bf16(a0, bfr[ni], acc[mi][ni], 0, 0, 0);
        acc[mi][ni] = __builtin_amdgcn_mfma_f32_16x16x32_bf16(a1, bfr[ni], acc[mi][ni], 0, 0, 0);
        acc[mi][ni] = __builtin_amdgcn_mfma_f32_16x16x32_bf16(a2, bfr[ni], acc[mi][ni], 0, 0, 0);
      }
    }
    __syncthreads();                     // single barrier per K-step; drain is cheap (issued early)
  }

  // staging LDS now dead; reuse as exchange
  if (tw == 0) {                   // t0 waves publish raw accumulators
    #pragma unroll
    for (int mi = 0; mi < 4; mi++)
      #pragma unroll
      for (int r = 0; r < 4; r++)
        #pragma unroll
        for (int ni = 0; ni < 4; ni++)
          yl[(size_t)(wm + mi * 16 + quad * 4 + r) * 65 + ni * 16 + l16] = acc[mi][ni][r];
  }
  __syncthreads();
  if (tw == 1) {                   // t1 waves apply BN + 2-step LIF, write both planes + bits
    #pragma unroll
    for (int mi = 0; mi < 4; mi++) {
      #pragma unroll
      for (int r = 0; r < 4; r++) {
        const int lrow = wm + mi * 16 + quad * 4 + r;
        const int orow = mt * 128 + lrow;
        const float iv = invv[orow], sh = shv[orow];
        const int widx = orow >> 8, c = orow & 255;
        float* dst = (widx == 0) ? dq : (widx == 1) ? dk : dv;
        unsigned short* bb = (widx == 0) ? qbits : (widx == 1) ? kbits : vbits;
        #pragma unroll
        for (int ni = 0; ni < 4; ni++) {
          const int n = nt * 64 + ni * 16 + l16;
          float y0 = yl[(size_t)lrow * 65 + ni * 16 + l16] * iv + sh;
          float y1 = acc[mi][ni][r] * iv + sh;
          float v1 = y0 * 0.5f;
          float s0 = (v1 >= 1.0f) ? 1.0f : 0.0f;
          float vr = v1 * (1.0f - s0);
          float v2 = vr + (y1 - vr) * 0.5f;
          float s1 = (v2 >= 1.0f) ? 1.0f : 0.0f;
          dst[(size_t)(b * NC + c) * NN + n] = s0;
          dst[(size_t)((NB + b) * NC + c) * NN + n] = s1;
          unsigned long long bl0 = __ballot(s0 != 0.0f);   // bit(lane)=quad*16+l16
          unsigned long long bl1 = __ballot(s1 != 0.0f);
          if (l16 == 0) {          // field quad = 16 n-bits of this lane's row c
            const int w16 = nt * 4 + ni;
            bb[(size_t)b        * 65536 + (size_t)c * 256 + w16] = (unsigned short)(bl0 >> (quad * 16));
            bb[(size_t)(NB + b) * 65536 + (size_t)c * 256 + w16] = (unsigned short)(bl1 >> (quad * 16));
          }
        }
      }
    }
  }
}

// ---------- kernel 4: kv = K^T V via popcount over bit-planes (exact integers) ----------
__global__ __launch_bounds__(256) void kv_kernel(const unsigned long long* __restrict__ kb,
                                                 const unsigned long long* __restrict__ vb,
                                                 float* __restrict__ kvout)
{
  __shared__ unsigned long long Kl[32 * 65];   // pitch 65 u64
  __shared__ unsigned long long Vl[32 * 65];
  const int h = blockIdx.x, z = blockIdx.y;    // z = t*16+b
  const int tid = threadIdx.x;
  for (int i = tid; i < 2048; i += 256) {
    int row = i >> 6, w = i & 63;
    size_t g = (size_t)z * 16384 + (size_t)(h * 32 + row) * 64 + w;
    Kl[row * 65 + w] = kb[g];
    Vl[row * 65 + w] = vb[g];
  }
  __syncthreads();
  const int d = tid & 31, e0 = tid >> 5;       // thread: row d x 4 cols (e0+8p)
  int acc0 = 0, acc1 = 0, acc2 = 0, acc3 = 0;
  for (int w = 0; w < 64; w++) {
    unsigned long long ku = Kl[d * 65 + w];
    acc0 += __popcll(ku & Vl[(e0     ) * 65 + w]);
    acc1 += __popcll(ku & Vl[(e0 +  8) * 65 + w]);
    acc2 += __popcll(ku & Vl[(e0 + 16) * 65 + w]);
    acc3 += __popcll(ku & Vl[(e0 + 24) * 65 + w]);
  }
  float* o = kvout + ((size_t)(z * NHD + h) << 10);
  o[d * 32 + e0     ] = (float)acc0;
  o[d * 32 + e0 +  8] = (float)acc1;
  o[d * 32 + e0 + 16] = (float)acc2;
  o[d * 32 + e0 + 24] = (float)acc3;
}

// ---------- kernel 5: attn = 0.125*(q@kv) via exact-integer MFMA, LIF(0.5) -> s bit-plane ----------
__global__ __launch_bounds__(256) void attn_kernel(const unsigned short* __restrict__ qb16,
                                                   const float* __restrict__ kvout,
                                                   unsigned short* __restrict__ sb16)
{
  __shared__ float kvl[2][32][33];
  __shared__ unsigned short qt[2][32][16];    // q bit-words: [t][d][n-word]
  const int nb = blockIdx.x, h = blockIdx.y, b = blockIdx.z;
  const int tid = threadIdx.x;
  const int wave = tid >> 6, lane = tid & 63, quad = lane >> 4, l16 = lane & 15;
  for (int i = tid; i < 2048; i += 256) {
    int t = i >> 10, j = i & 1023;
    kvl[t][j >> 5][j & 31] = kvout[((size_t)((t * NB + b) * NHD + h) << 10) + j];
  }
  for (int i = tid; i < 1024; i += 256) {
    int t = i >> 9, j = i & 511, row = j >> 4, w = j & 15;
    qt[t][row][w] = qb16[(size_t)(t * NB + b) * 65536 + (size_t)(h * 32 + row) * 256 + nb * 16 + w];
  }
  __syncthreads();
  // B-frags: kv split into exact bf16 hi+lo (integers <=4096; |lo|<=8; both exact)
  short8 bf[2][2][2];
  #pragma unroll
  for (int t = 0; t < 2; t++) {
    #pragma unroll
    for (int eh = 0; eh < 2; eh++) {
      short8 bh, bl;
      #pragma unroll
      for (int j = 0; j < 8; j++) {
        float v = kvl[t][quad * 8 + j][eh * 16 + l16];
        unsigned short h0 = f2bf(v);
        float lo = v - bfb2f(h0);
        bh[j] = (short)h0;
        bl[j] = (short)f2bf(lo);
      }
      bf[t][0][eh] = bh; bf[t][1][eh] = bl;
    }
  }
  floatx4 acc[2][4][2] = {};                   // [t][ntile][ehalf]
  #pragma unroll
  for (int t = 0; t < 2; t++) {
    #pragma unroll
    for (int nt = 0; nt < 4; nt++) {
      const int wv = wave * 4 + nt;            // n-word index of this tile
      short8 af;
      #pragma unroll
      for (int j = 0; j < 8; j++) {            // broadcast u16 read + per-lane bit test
        unsigned short w = qt[t][quad * 8 + j][wv];
        af[j] = (short)(((w >> l16) & 1) ? 0x3F80 : 0);
      }
      #pragma unroll
      for (int eh = 0; eh < 2; eh++) {
        acc[t][nt][eh] = __builtin_amdgcn_mfma_f32_16x16x32_bf16(af, bf[t][0][eh], acc[t][nt][eh], 0, 0, 0);
        acc[t][nt][eh] = __builtin_amdgcn_mfma_f32_16x16x32_bf16(af, bf[t][1][eh], acc[t][nt][eh], 0, 0, 0);
      }
    }
  }
  // epilogue: exact dyadic LIF(0.5); pack spikes as bits (16 c per n-row)
  const int n0 = nb * 256 + wave * 64;
  #pragma unroll
  for (int nt = 0; nt < 4; nt++) {
    #pragma unroll
    for (int r = 0; r < 4; r++) {
      const int n = n0 + nt * 16 + quad * 4 + r;          // per-lane (quad)
      #pragma unroll
      for (int eh = 0; eh < 2; eh++) {
        float a0 = acc[0][nt][eh][r] * 0.125f;            // exact dyadic
        float a1 = acc[1][nt][eh][r] * 0.125f;
        float v1 = a0 * 0.5f;
        float s0 = (v1 >= 0.5f) ? 1.f : 0.f;
        float vr = v1 * (1.f - s0);
        float v2 = vr + (a1 - vr) * 0.5f;
        float s1 = (v2 >= 0.5f) ? 1.f : 0.f;
        unsigned long long bl0 = __ballot(s0 != 0.f);     // field quad = 16 c-bits of n(quad)
        unsigned long long bl1 = __ballot(s1 != 0.f);
        if (l16 == 0) {
          const int w16 = h * 2 + eh;
          sb16[(size_t)b        * 65536 + (size_t)n * 16 + w16] = (unsigned short)(bl0 >> (quad * 16));
          sb16[(size_t)(NB + b) * 65536 + (size_t)n * 16 + w16] = (unsigned short)(bl1 >> (quad * 16));
        }
      }
    }
  }
}

// ---------- kernel 6: out = BN(Wp @ s + bp); same 2-phase prefetch pipeline ----------
__global__ __launch_bounds__(256, 2) void p_gemm(
    const unsigned short* __restrict__ sb16,  // [z][n][c-word] bit-plane
    const unsigned short* __restrict__ Wsp,   // [3][256][256]
    const float* __restrict__ invv, const float* __restrict__ shv,
    float* __restrict__ dout)
{
  __shared__ __align__(16) unsigned char smem[65536];
  const int nt = blockIdx.x, mt = blockIdx.y, z = blockIdx.z;  // z = t*16+b
  const int tid = threadIdx.x;
  const int lane = tid & 63, quad = lane >> 4, l16 = lane & 15;
  const int wave = tid >> 6;
  const int wm = (wave & 1) * 64, wn = (wave >> 1) * 64;
  floatx4 acc[4][4] = {};
  const int brow = tid & 127, bhalf = tid >> 7;

  // hoisted B bit-word preload: 32 B per thread covers all 8 K-steps
  const unsigned short* srowbase = sb16 + (size_t)z * 65536 + (size_t)(nt * 128 + brow) * 16;
  uintx4 sw0 = *(const uintx4*)(srowbase);
  uintx4 sw1 = *(const uintx4*)(srowbase + 8);

  // prologue: stage K-step 0 into buffer 0
  {
    #pragma unroll
    for (int j = 0; j < 6; j++) {
      int ci = j * 256 + tid;
      int fr = ci >> 2;
      int kk = (ci & 3) ^ ((fr >> 1) & 3);
      int s = fr >> 7, row = fr & 127;
      const unsigned short* g = Wsp + (size_t)s * 65536 + (size_t)(mt * 128 + row) * 256 + 0 + kk * 8;
      gld_lds16(g, (unsigned short*)smem + (size_t)ci * 8);
    }
    unsigned int w32 = sw0[0];
    unsigned int wb = bhalf ? (w32 >> 16) : (w32 & 0xFFFFu);
    stage_bits(wb, brow, bhalf, (unsigned short*)(smem + 49152));
  }
  __syncthreads();

  #pragma unroll
  for (int it = 0; it < 8; ++it) {
    unsigned short* Ac = (unsigned short*)(smem + (it & 1) * 24576);
    unsigned short* Bc = (unsigned short*)(smem + 49152 + (it & 1) * 8192);
    if (it < 7) {
      unsigned short* An = (unsigned short*)(smem + ((it + 1) & 1) * 24576);
      const int k0 = (it + 1) * 32;
      #pragma unroll
      for (int j = 0; j < 6; j++) {
        int ci = j * 256 + tid;
        int fr = ci >> 2;
        int kk = (ci & 3) ^ ((fr >> 1) & 3);
        int s = fr >> 7, row = fr & 127;
        const unsigned short* g = Wsp + (size_t)s * 65536 + (size_t)(mt * 128 + row) * 256 + k0 + kk * 8;
        gld_lds16(g, An + (size_t)ci * 8);
      }
    }
    __builtin_amdgcn_sched_barrier(0);

    short8 bfr[4];
    #pragma unroll
    for (int ni = 0; ni < 4; ni++) {
      int fr = wn + ni * 16 + l16;
      bfr[ni] = *(const short8*)(Bc + (size_t)swz(fr, quad) * 8);
    }
    if (it < 7) {
      unsigned short* Bn = (unsigned short*)(smem + 49152 + (((it + 1) & 1)) * 8192);
      unsigned int w32 = ((it + 1) < 4) ? sw0[(it + 1) & 3] : sw1[(it + 1) & 3];
      unsigned int wb = bhalf ? (w32 >> 16) : (w32 & 0xFFFFu);
      stage_bits(wb, brow, bhalf, Bn);
    }
    #pragma unroll
    for (int mi = 0; mi < 4; mi++) {
      const int r0 = wm + mi * 16 + l16;
      short8 a0 = *(const short8*)(Ac + (size_t)swz(      r0, quad) * 8);
      short8 a1 = *(const short8*)(Ac + (size_t)swz(128 + r0, quad) * 8);
      short8 a2 = *(const short8*)(Ac + (size_t)swz(256 + r0, quad) * 8);
      #pragma unroll
      for (int ni = 0; ni < 4; ni++) {
        acc[mi][ni] = __builtin_amdgcn_mfma_f32_16x16x32_bf16(a0, bfr[ni], acc[mi][ni], 0, 0, 0);
        acc[mi][ni] = __builtin_amdgcn_mfma_f32_16x16x32_bf16(a1, bfr[ni], acc[mi][ni], 0, 0, 0);
        acc[mi][ni] = __builtin_amdgcn_mfma_f32_16x16x32_bf16(a2, bfr[ni], acc[mi][ni], 0, 0, 0);
      }
    }
    __syncthreads();
  }

  #pragma unroll
  for (int mi = 0; mi < 4; mi++) {
    #pragma unroll
    for (int r = 0; r < 4; r++) {
      const int orow = mt * 128 + wm + mi * 16 + quad * 4 + r;
      const float iv = invv[orow], sh = shv[orow];
      #pragma unroll
      for (int ni = 0; ni < 4; ni++) {
        const int n = nt * 128 + wn + ni * 16 + l16;
        dout[((size_t)(z * NC + orow)) * NN + n] = acc[mi][ni][r] * iv + sh;
      }
    }
  }
}

// ---------- launch ----------
extern "C" void kernel_launch(void* const* d_in, const int* in_sizes, int n_in,
                              void* d_out, int out_size, void* d_ws, size_t ws_size,
                              hipStream_t stream) {
  (void)in_sizes; (void)n_in; (void)out_size; (void)ws_size;
  const float* x  = (const float*)d_in[0];
  const float* wq = (const float*)d_in[1];
  const float* wk = (const float*)d_in[2];
  const float* wv = (const float*)d_in[3];
  const float* wp = (const float*)d_in[4];
  const float* bp = (const float*)d_in[5];
  const float* qg = (const float*)d_in[6],  *qb = (const float*)d_in[7];
  const float* qm = (const float*)d_in[8],  *qva = (const float*)d_in[9];
  const float* kg = (const float*)d_in[10], *kb = (const float*)d_in[11];
  const float* km = (const float*)d_in[12], *kva = (const float*)d_in[13];
  const float* vg = (const float*)d_in[14], *vb = (const float*)d_in[15];
  const float* vm = (const float*)d_in[16], *vva = (const float*)d_in[17];
  const float* pg = (const float*)d_in[18], *pb = (const float*)d_in[19];
  const float* pm = (const float*)d_in[20], *pva = (const float*)d_in[21];

  float* out = (float*)d_out;       // outputs in return order
  float* xs  = out + NE1;
  float* dq  = out + 2 * NE1;
  float* dk  = out + 3 * NE1;
  float* dv  = out + 4 * NE1;

  char* ws = (char*)d_ws;
  unsigned short* xbits = (unsigned short*)ws;                  // 4194304 B
  unsigned short* Wqkv  = (unsigned short*)(ws + 4194304);      // 1179648 B
  unsigned short* Wp    = (unsigned short*)(ws + 5373952);      // 393216 B
  float* kvout          = (float*)(ws + 5767168);               // 1048576 B
  unsigned short* qbits = (unsigned short*)(ws + 6815744);      // 4194304 B
  unsigned short* kbits = (unsigned short*)(ws + 11010048);     // 4194304 B
  unsigned short* vbits = (unsigned short*)(ws + 15204352);     // 4194304 B
  unsigned short* sbits = (unsigned short*)(ws + 19398656);     // 4194304 B
  float* invqkv         = (float*)(ws + 23592960);              // 768 floats
  float* shqkv          = invqkv + 768;
  float* invp           = shqkv + 768;
  float* shp            = invp + 256;

  prep_kernel<<<1028, 256, 0, stream>>>(wq, wk, wv, wp, bp,
                                        qg, qb, qm, qva, kg, kb, km, kva,
                                        vg, vb, vm, vva, pg, pb, pm, pva,
                                        Wqkv, Wp, invqkv, shqkv, invp, shp);
  lifx_kernel<<<dim3(64, 4, 16), 256, 0, stream>>>(x, xs, xbits);
  qkv_gemm<<<dim3(64, 6, 16), 256, 0, stream>>>(xbits, Wqkv, invqkv, shqkv,
                                                dq, dk, dv, qbits, kbits, vbits);
  kv_kernel<<<dim3(8, 32), 256, 0, stream>>>((const unsigned long long*)kbits,
                                             (const unsigned long long*)vbits, kvout);
  attn_kernel<<<dim3(16, 8, 16), 256, 0, stream>>>(qbits, kvout, sbits);
  p_gemm<<<dim3(32, 2, 32), 256, 0, stream>>>(sbits, Wp, invp, shp, out);
}

// Round 2
// 939.671 us; speedup vs baseline: 1.0648x; 1.0648x over previous
//
#include <hip/hip_runtime.h>
#include <cstdint>
#include <cstddef>

typedef __attribute__((ext_vector_type(8))) short short8;       // 8 x bf16 bits (MFMA A/B frag)
typedef __attribute__((ext_vector_type(4))) float floatx4;      // MFMA C/D frag
typedef __attribute__((ext_vector_type(4))) unsigned int uintx4;

#define DEV static __device__ __forceinline__

constexpr int NT = 2, NB = 16, NC = 256, NN = 4096, NHD = 8;
constexpr size_t NE1 = (size_t)NT * NB * NC * NN;   // elements per output tensor
constexpr size_t TSTRIDE = (size_t)NB * NC * NN;    // t-stride in elements

// ---------- helpers ----------
DEV unsigned short f2bf(float x) {            // round-to-nearest-even fp32 -> bf16 bits
  unsigned int u = __builtin_bit_cast(unsigned int, x);
  unsigned int lsb = (u >> 16) & 1u;
  u += 0x7FFFu + lsb;
  return (unsigned short)(u >> 16);
}
DEV float bfb2f(unsigned short h) {
  unsigned int u = ((unsigned int)h) << 16;
  return __builtin_bit_cast(float, u);
}
DEV unsigned int pk2(unsigned short a, unsigned short b) {
  return (unsigned int)a | ((unsigned int)b << 16);
}
// bank-conflict-free slot mapping for [rows][32 bf16] tiles: chunk kk (16B) of row fr
// lives at slot fr*4 + (kk ^ ((fr>>1)&3)).
DEV int swz(int fr, int kk) { return fr * 4 + (kk ^ ((fr >> 1) & 3)); }
// async global->LDS, 16B per lane; LDS dest is wave-uniform base + lane*16
typedef __attribute__((address_space(3))) unsigned int lds_u32;
typedef __attribute__((address_space(1))) const unsigned int glb_u32;
DEV void gld_lds16(const void* g, void* l) {
  __builtin_amdgcn_global_load_lds((glb_u32*)g, (lds_u32*)l, 16, 0, 0);
}
// B-unpack: 16 spike bits -> 16 bf16 (two 16B chunks) written to swizzled slots
DEV void stage_bits(unsigned int wb, int fr, int bhalf, unsigned short* Bdst) {
  uintx4 c0v, c1v;
  #pragma unroll
  for (int p = 0; p < 4; p++) {
    c0v[p] = pk2(((wb >> (2 * p)) & 1) ? 0x3F80 : 0, ((wb >> (2 * p + 1)) & 1) ? 0x3F80 : 0);
    c1v[p] = pk2(((wb >> (8 + 2 * p)) & 1) ? 0x3F80 : 0, ((wb >> (9 + 2 * p)) & 1) ? 0x3F80 : 0);
  }
  *(uintx4*)(Bdst + (size_t)swz(fr, bhalf * 2)     * 8) = c0v;
  *(uintx4*)(Bdst + (size_t)swz(fr, bhalf * 2 + 1) * 8) = c1v;
}

// ---------- kernel 1: weight split + BN constant prep ----------
__global__ __launch_bounds__(256) void prep_kernel(
    const float* __restrict__ wq, const float* __restrict__ wk, const float* __restrict__ wv,
    const float* __restrict__ wp, const float* __restrict__ bp,
    const float* __restrict__ qg, const float* __restrict__ qb, const float* __restrict__ qm, const float* __restrict__ qva,
    const float* __restrict__ kg, const float* __restrict__ kb, const float* __restrict__ km, const float* __restrict__ kva,
    const float* __restrict__ vg, const float* __restrict__ vb, const float* __restrict__ vm, const float* __restrict__ vva,
    const float* __restrict__ pg, const float* __restrict__ pb, const float* __restrict__ pm, const float* __restrict__ pva,
    unsigned short* __restrict__ Wqkv, unsigned short* __restrict__ Wp,
    float* __restrict__ invqkv, float* __restrict__ shqkv,
    float* __restrict__ invp, float* __restrict__ shp)
{
  int idx = blockIdx.x * 256 + threadIdx.x;
  if (idx < 196608) {                       // Wq|Wk|Wv stacked [768][256], 3-way bf16 split
    int o = idx >> 8, c = idx & 255;
    const float* src = (o < 256) ? wq : (o < 512) ? wk : wv;
    float w = src[(size_t)(o & 255) * 256 + c];
    unsigned short h0 = f2bf(w);  float f0 = bfb2f(h0);
    float r1 = w - f0;
    unsigned short h1 = f2bf(r1); float f1 = bfb2f(h1);
    float r2 = r1 - f1;
    unsigned short h2 = f2bf(r2);
    Wqkv[idx] = h0; Wqkv[196608 + idx] = h1; Wqkv[393216 + idx] = h2;
  } else if (idx < 262144) {                // Wp [256][256], 3-way split
    int j = idx - 196608;
    float w = wp[j];
    unsigned short h0 = f2bf(w);  float f0 = bfb2f(h0);
    float r1 = w - f0;
    unsigned short h1 = f2bf(r1); float f1 = bfb2f(h1);
    float r2 = r1 - f1;
    unsigned short h2 = f2bf(r2);
    Wp[j] = h0; Wp[65536 + j] = h1; Wp[131072 + j] = h2;
  } else if (idx < 262912) {                // BN constants for q,k,v stacked [768]
    int i = idx - 262144;
    int p = i >> 8, c = i & 255;
    float g  = (p == 0) ? qg[c] : (p == 1) ? kg[c] : vg[c];
    float be = (p == 0) ? qb[c] : (p == 1) ? kb[c] : vb[c];
    float mn = (p == 0) ? qm[c] : (p == 1) ? km[c] : vm[c];
    float vr = (p == 0) ? qva[c] : (p == 1) ? kva[c] : vva[c];
    float sq = sqrtf(vr + 1e-5f);
    invqkv[i] = g / sq;
    shqkv[i]  = be - (mn * g) / sq;
  } else if (idx < 263168) {                // BN constants for p, bias folded in
    int c = idx - 262912;
    float sq = sqrtf(pva[c] + 1e-5f);
    float iv = pg[c] / sq;
    invp[c] = iv;
    shp[c]  = pb[c] - (pm[c] * pg[c]) / sq + bp[c] * iv;
  }
}

// ---------- kernel 2: LIF on x -> xs (fp32 [t,b,c,n]) + bit-plane xbits [z][n][c-word] ----------
__global__ __launch_bounds__(256) void lifx_kernel(const float* __restrict__ x,
                                                   float* __restrict__ xs_out,
                                                   unsigned short* __restrict__ xb16)
{
  __shared__ float tile[2][64][65];
  const int nt = blockIdx.x, ct = blockIdx.y, b = blockIdx.z;
  const int tid = threadIdx.x;
  const int ci = tid >> 2, cq = tid & 3;
  const int n0 = nt * 64, c0 = ct * 64;
  const size_t rowbase = ((size_t)(b * NC + c0 + ci)) * NN + n0 + cq * 16;
  const float* px0 = x + rowbase;
  const float* px1 = x + rowbase + TSTRIDE;
  float* po0 = xs_out + rowbase;
  float* po1 = xs_out + rowbase + TSTRIDE;
  #pragma unroll
  for (int jj = 0; jj < 4; jj++) {
    floatx4 x0 = *(const floatx4*)(px0 + jj * 4);
    floatx4 x1 = *(const floatx4*)(px1 + jj * 4);
    floatx4 s0v, s1v;
    #pragma unroll
    for (int e = 0; e < 4; e++) {
      float v1 = x0[e] * 0.5f;                       // exact
      float s0 = (v1 >= 1.0f) ? 1.0f : 0.0f;
      float vr = v1 * (1.0f - s0);                   // exact (0 or v1)
      float v2 = vr + (x1[e] - vr) * 0.5f;           // same rounding as reference
      float s1 = (v2 >= 1.0f) ? 1.0f : 0.0f;
      s0v[e] = s0; s1v[e] = s1;
      tile[0][ci][cq * 16 + jj * 4 + e] = s0;
      tile[1][ci][cq * 16 + jj * 4 + e] = s1;
    }
    *(floatx4*)(po0 + jj * 4) = s0v;
    *(floatx4*)(po1 + jj * 4) = s1v;
  }
  __syncthreads();
  const int ni = tid >> 2, cg = tid & 3;   // thread owns row n0+ni, c-word (c0>>4)+cg
  #pragma unroll
  for (int t = 0; t < 2; t++) {
    unsigned int wbits = 0;
    #pragma unroll
    for (int j = 0; j < 16; j++)
      wbits |= (tile[t][cg * 16 + j][ni] != 0.f ? 1u : 0u) << j;
    xb16[((size_t)((t * NB + b) * NN) + n0 + ni) * 16 + (c0 >> 4) + cg] = (unsigned short)wbits;
  }
}

// ---------- kernel 3: fused QKV GEMM + BN + LIF -> fp32 spikes + bit-planes ----------
// Round-0 single-buffer structure (3 blocks/CU) + hoisted B bit-word register preload
// + ALL-WAVE two-pass epilogue (halved per-thread store/ballot/LIF work).
// MFMA operand values and per-accumulator instruction order unchanged => bit-identical.
__global__ __launch_bounds__(256, 3) void qkv_gemm(
    const unsigned short* __restrict__ xb16,  // [z][n][16 c-words] bit-plane
    const unsigned short* __restrict__ Wsp,   // [3 splits][768][256] bf16
    const float* __restrict__ invv, const float* __restrict__ shv,  // [768]
    float* __restrict__ dq, float* __restrict__ dk, float* __restrict__ dv,
    unsigned short* __restrict__ qbits, unsigned short* __restrict__ kbits,
    unsigned short* __restrict__ vbits)
{
  __shared__ __align__(16) unsigned char smem[33280];
  unsigned short* Al = (unsigned short*)smem;            // 1536 slots (3 splits x 128 rows x 4)
  unsigned short* Bl = (unsigned short*)(smem + 24576);  // 512 slots (2t x 64 rows x 4)
  float* yl = (float*)smem;                              // overlay: 2 x [64][65] floats
  const int nt = blockIdx.x, mt = blockIdx.y, b = blockIdx.z;
  const int tid = threadIdx.x;
  const int lane = tid & 63, quad = lane >> 4, l16 = lane & 15;
  const int wave = tid >> 6;
  const int wm = (wave & 1) * 64, tw = wave >> 1;        // waves 0,1: t=0 ; waves 2,3: t=1
  floatx4 acc[4][4] = {};
  const int bt = tid >> 7, brow = (tid >> 1) & 63, bhalf = tid & 1;
  const int frB = bt * 64 + brow;

  // hoisted B bit-word preload: 32 B per thread covers all 8 K-steps
  const unsigned short* xrowbase = xb16 + ((size_t)((bt * NB + b) * NN) + nt * 64 + brow) * 16;
  uintx4 xw0 = *(const uintx4*)(xrowbase);
  uintx4 xw1 = *(const uintx4*)(xrowbase + 8);

  #pragma unroll
  for (int it = 0; it < 8; ++it) {
    const int k0 = it * 32;
    __syncthreads();
    #pragma unroll
    for (int j = 0; j < 6; j++) {            // A: async copy, swizzled slots
      int ci = j * 256 + tid;
      int fr = ci >> 2;
      int kk = (ci & 3) ^ ((fr >> 1) & 3);
      int s = fr >> 7, row = fr & 127;
      const unsigned short* g = Wsp + (size_t)s * 196608 + (size_t)(mt * 128 + row) * 256 + k0 + kk * 8;
      gld_lds16(g, Al + (size_t)ci * 8);
    }
    {                                        // B: unpack 16 bits from REGISTER preload
      unsigned int w32 = (it < 4) ? xw0[it & 3] : xw1[it & 3];
      unsigned int wb = bhalf ? (w32 >> 16) : (w32 & 0xFFFFu);
      stage_bits(wb, frB, bhalf, Bl);
    }
    __syncthreads();

    short8 bfr[4];
    #pragma unroll
    for (int ni = 0; ni < 4; ni++) {
      int fr = tw * 64 + ni * 16 + l16;
      bfr[ni] = *(const short8*)(Bl + (size_t)swz(fr, quad) * 8);
    }
    #pragma unroll
    for (int mi = 0; mi < 4; mi++) {
      const int r0 = wm + mi * 16 + l16;
      short8 a0 = *(const short8*)(Al + (size_t)swz(      r0, quad) * 8);
      short8 a1 = *(const short8*)(Al + (size_t)swz(128 + r0, quad) * 8);
      short8 a2 = *(const short8*)(Al + (size_t)swz(256 + r0, quad) * 8);
      #pragma unroll
      for (int ni = 0; ni < 4; ni++) {
        acc[mi][ni] = __builtin_amdgcn_mfma_f32_16x16x32_bf16(a0, bfr[ni], acc[mi][ni], 0, 0, 0);
        acc[mi][ni] = __builtin_amdgcn_mfma_f32_16x16x32_bf16(a1, bfr[ni], acc[mi][ni], 0, 0, 0);
        acc[mi][ni] = __builtin_amdgcn_mfma_f32_16x16x32_bf16(a2, bfr[ni], acc[mi][ni], 0, 0, 0);
      }
    }
  }
  __syncthreads();                 // staging LDS now dead; reuse as exchange
  // two-pass all-wave epilogue: pass p covers rows p*64..p*64+63.
  // waves p (t0) and p+2 (t1) publish their accs; then ALL waves process 16 rows each.
  float* buf0 = yl;                // [64][65] t0 raw accs
  float* buf1 = yl + 64 * 65;      // [64][65] t1 raw accs
  #pragma unroll
  for (int pass = 0; pass < 2; ++pass) {
    if (wave == pass || wave == pass + 2) {
      float* bufd = (wave == pass) ? buf0 : buf1;
      #pragma unroll
      for (int mi = 0; mi < 4; mi++)
        #pragma unroll
        for (int r = 0; r < 4; r++)
          #pragma unroll
          for (int ni = 0; ni < 4; ni++)
            bufd[(size_t)(mi * 16 + quad * 4 + r) * 65 + ni * 16 + l16] = acc[mi][ni][r];
    }
    __syncthreads();
    #pragma unroll
    for (int r = 0; r < 4; r++) {
      const int lcl = wave * 16 + quad * 4 + r;          // 0..63 within pass
      const int lrow = pass * 64 + lcl;
      const int orow = mt * 128 + lrow;
      const float iv = invv[orow], sh = shv[orow];
      const int widx = orow >> 8, c = orow & 255;
      float* dst = (widx == 0) ? dq : (widx == 1) ? dk : dv;
      unsigned short* bb = (widx == 0) ? qbits : (widx == 1) ? kbits : vbits;
      #pragma unroll
      for (int ni = 0; ni < 4; ni++) {
        const int n = nt * 64 + ni * 16 + l16;
        float y0 = buf0[(size_t)lcl * 65 + ni * 16 + l16] * iv + sh;
        float y1 = buf1[(size_t)lcl * 65 + ni * 16 + l16] * iv + sh;
        float v1 = y0 * 0.5f;
        float s0 = (v1 >= 1.0f) ? 1.0f : 0.0f;
        float vr = v1 * (1.0f - s0);
        float v2 = vr + (y1 - vr) * 0.5f;
        float s1 = (v2 >= 1.0f) ? 1.0f : 0.0f;
        dst[(size_t)(b * NC + c) * NN + n] = s0;
        dst[(size_t)((NB + b) * NC + c) * NN + n] = s1;
        unsigned long long bl0 = __ballot(s0 != 0.0f);   // bit(lane)=quad*16+l16
        unsigned long long bl1 = __ballot(s1 != 0.0f);
        if (l16 == 0) {          // field quad = 16 n-bits of this lane's row c
          const int w16 = nt * 4 + ni;
          bb[(size_t)b        * 65536 + (size_t)c * 256 + w16] = (unsigned short)(bl0 >> (quad * 16));
          bb[(size_t)(NB + b) * 65536 + (size_t)c * 256 + w16] = (unsigned short)(bl1 >> (quad * 16));
        }
      }
    }
    __syncthreads();             // protect exchange buffers before next pass publish
  }
}

// ---------- kernel 4: kv = K^T V via popcount over bit-planes (exact integers) ----------
__global__ __launch_bounds__(256) void kv_kernel(const unsigned long long* __restrict__ kb,
                                                 const unsigned long long* __restrict__ vb,
                                                 float* __restrict__ kvout)
{
  __shared__ unsigned long long Kl[32 * 65];   // pitch 65 u64
  __shared__ unsigned long long Vl[32 * 65];
  const int h = blockIdx.x, z = blockIdx.y;    // z = t*16+b
  const int tid = threadIdx.x;
  for (int i = tid; i < 2048; i += 256) {
    int row = i >> 6, w = i & 63;
    size_t g = (size_t)z * 16384 + (size_t)(h * 32 + row) * 64 + w;
    Kl[row * 65 + w] = kb[g];
    Vl[row * 65 + w] = vb[g];
  }
  __syncthreads();
  const int d = tid & 31, e0 = tid >> 5;       // thread: row d x 4 cols (e0+8p)
  int acc0 = 0, acc1 = 0, acc2 = 0, acc3 = 0;
  for (int w = 0; w < 64; w++) {
    unsigned long long ku = Kl[d * 65 + w];
    acc0 += __popcll(ku & Vl[(e0     ) * 65 + w]);
    acc1 += __popcll(ku & Vl[(e0 +  8) * 65 + w]);
    acc2 += __popcll(ku & Vl[(e0 + 16) * 65 + w]);
    acc3 += __popcll(ku & Vl[(e0 + 24) * 65 + w]);
  }
  float* o = kvout + ((size_t)(z * NHD + h) << 10);
  o[d * 32 + e0     ] = (float)acc0;
  o[d * 32 + e0 +  8] = (float)acc1;
  o[d * 32 + e0 + 16] = (float)acc2;
  o[d * 32 + e0 + 24] = (float)acc3;
}

// ---------- kernel 5: attn = 0.125*(q@kv) via exact-integer MFMA, LIF(0.5) -> s bit-plane ----------
__global__ __launch_bounds__(256) void attn_kernel(const unsigned short* __restrict__ qb16,
                                                   const float* __restrict__ kvout,
                                                   unsigned short* __restrict__ sb16)
{
  __shared__ float kvl[2][32][33];
  __shared__ __align__(16) unsigned short qt[2][16][32];  // q bit-words TRANSPOSED: [t][n-word][d]
  const int nb = blockIdx.x, h = blockIdx.y, b = blockIdx.z;
  const int tid = threadIdx.x;
  const int wave = tid >> 6, lane = tid & 63, quad = lane >> 4, l16 = lane & 15;
  for (int i = tid; i < 2048; i += 256) {
    int t = i >> 10, j = i & 1023;
    kvl[t][j >> 5][j & 31] = kvout[((size_t)((t * NB + b) * NHD + h) << 10) + j];
  }
  for (int i = tid; i < 1024; i += 256) {
    int t = i >> 9, j = i & 511, row = j >> 4, w = j & 15;
    qt[t][w][row] = qb16[(size_t)(t * NB + b) * 65536 + (size_t)(h * 32 + row) * 256 + nb * 16 + w];
  }
  __syncthreads();
  // B-frags: kv split into exact bf16 hi+lo (integers <=4096; |lo|<=8; both exact)
  short8 bf[2][2][2];
  #pragma unroll
  for (int t = 0; t < 2; t++) {
    #pragma unroll
    for (int eh = 0; eh < 2; eh++) {
      short8 bh, bl;
      #pragma unroll
      for (int j = 0; j < 8; j++) {
        float v = kvl[t][quad * 8 + j][eh * 16 + l16];
        unsigned short h0 = f2bf(v);
        float lo = v - bfb2f(h0);
        bh[j] = (short)h0;
        bl[j] = (short)f2bf(lo);
      }
      bf[t][0][eh] = bh; bf[t][1][eh] = bl;
    }
  }
  floatx4 acc[2][4][2] = {};                   // [t][ntile][ehalf]
  #pragma unroll
  for (int t = 0; t < 2; t++) {
    #pragma unroll
    for (int nt = 0; nt < 4; nt++) {
      const int wv = wave * 4 + nt;            // n-word index of this tile
      short8 qw = *(const short8*)(&qt[t][wv][quad * 8]);  // one b128 broadcast read
      short8 af;
      #pragma unroll
      for (int j = 0; j < 8; j++)              // per-lane bit test
        af[j] = (short)((((unsigned short)qw[j] >> l16) & 1) ? 0x3F80 : 0);
      #pragma unroll
      for (int eh = 0; eh < 2; eh++) {
        acc[t][nt][eh] = __builtin_amdgcn_mfma_f32_16x16x32_bf16(af, bf[t][0][eh], acc[t][nt][eh], 0, 0, 0);
        acc[t][nt][eh] = __builtin_amdgcn_mfma_f32_16x16x32_bf16(af, bf[t][1][eh], acc[t][nt][eh], 0, 0, 0);
      }
    }
  }
  // epilogue: exact dyadic LIF(0.5); pack spikes as bits (16 c per n-row)
  const int n0 = nb * 256 + wave * 64;
  #pragma unroll
  for (int nt = 0; nt < 4; nt++) {
    #pragma unroll
    for (int r = 0; r < 4; r++) {
      const int n = n0 + nt * 16 + quad * 4 + r;          // per-lane (quad)
      #pragma unroll
      for (int eh = 0; eh < 2; eh++) {
        float a0 = acc[0][nt][eh][r] * 0.125f;            // exact dyadic
        float a1 = acc[1][nt][eh][r] * 0.125f;
        float v1 = a0 * 0.5f;
        float s0 = (v1 >= 0.5f) ? 1.f : 0.f;
        float vr = v1 * (1.f - s0);
        float v2 = vr + (a1 - vr) * 0.5f;
        float s1 = (v2 >= 0.5f) ? 1.f : 0.f;
        unsigned long long bl0 = __ballot(s0 != 0.f);     // field quad = 16 c-bits of n(quad)
        unsigned long long bl1 = __ballot(s1 != 0.f);
        if (l16 == 0) {
          const int w16 = h * 2 + eh;
          sb16[(size_t)b        * 65536 + (size_t)n * 16 + w16] = (unsigned short)(bl0 >> (quad * 16));
          sb16[(size_t)(NB + b) * 65536 + (size_t)n * 16 + w16] = (unsigned short)(bl1 >> (quad * 16));
        }
      }
    }
  }
}

// ---------- kernel 6: out = BN(Wp @ s + bp); round-0 structure + hoisted B preload ----------
__global__ __launch_bounds__(256, 3) void p_gemm(
    const unsigned short* __restrict__ sb16,  // [z][n][c-word] bit-plane
    const unsigned short* __restrict__ Wsp,   // [3][256][256]
    const float* __restrict__ invv, const float* __restrict__ shv,
    float* __restrict__ dout)
{
  __shared__ __align__(16) unsigned char smem[32768];
  unsigned short* Al = (unsigned short*)smem;            // 1536 slots
  unsigned short* Bl = (unsigned short*)(smem + 24576);  // 512 slots (128 rows x 4)
  const int nt = blockIdx.x, mt = blockIdx.y, z = blockIdx.z;  // z = t*16+b
  const int tid = threadIdx.x;
  const int lane = tid & 63, quad = lane >> 4, l16 = lane & 15;
  const int wave = tid >> 6;
  const int wm = (wave & 1) * 64, wn = (wave >> 1) * 64;
  floatx4 acc[4][4] = {};
  const int brow = tid & 127, bhalf = tid >> 7;

  // hoisted B bit-word preload: 32 B per thread covers all 8 K-steps
  const unsigned short* srowbase = sb16 + (size_t)z * 65536 + (size_t)(nt * 128 + brow) * 16;
  uintx4 sw0 = *(const uintx4*)(srowbase);
  uintx4 sw1 = *(const uintx4*)(srowbase + 8);

  #pragma unroll
  for (int it = 0; it < 8; ++it) {
    const int k0 = it * 32;
    __syncthreads();
    #pragma unroll
    for (int j = 0; j < 6; j++) {            // A via async copy, swizzled slots
      int ci = j * 256 + tid;
      int fr = ci >> 2;
      int kk = (ci & 3) ^ ((fr >> 1) & 3);
      int s = fr >> 7, row = fr & 127;
      const unsigned short* g = Wsp + (size_t)s * 65536 + (size_t)(mt * 128 + row) * 256 + k0 + kk * 8;
      gld_lds16(g, Al + (size_t)ci * 8);
    }
    {                                        // B: unpack 16 bits from REGISTER preload
      unsigned int w32 = (it < 4) ? sw0[it & 3] : sw1[it & 3];
      unsigned int wb = bhalf ? (w32 >> 16) : (w32 & 0xFFFFu);
      stage_bits(wb, brow, bhalf, Bl);
    }
    __syncthreads();

    short8 bfr[4];
    #pragma unroll
    for (int ni = 0; ni < 4; ni++) {
      int fr = wn + ni * 16 + l16;
      bfr[ni] = *(const short8*)(Bl + (size_t)swz(fr, quad) * 8);
    }
    #pragma unroll
    for (int mi = 0; mi < 4; mi++) {
      const int r0 = wm + mi * 16 + l16;
      short8 a0 = *(const short8*)(Al + (size_t)swz(      r0, quad) * 8);
      short8 a1 = *(const short8*)(Al + (size_t)swz(128 + r0, quad) * 8);
      short8 a2 = *(const short8*)(Al + (size_t)swz(256 + r0, quad) * 8);
      #pragma unroll
      for (int ni = 0; ni < 4; ni++) {
        acc[mi][ni] = __builtin_amdgcn_mfma_f32_16x16x32_bf16(a0, bfr[ni], acc[mi][ni], 0, 0, 0);
        acc[mi][ni] = __builtin_amdgcn_mfma_f32_16x16x32_bf16(a1, bfr[ni], acc[mi][ni], 0, 0, 0);
        acc[mi][ni] = __builtin_amdgcn_mfma_f32_16x16x32_bf16(a2, bfr[ni], acc[mi][ni], 0, 0, 0);
      }
    }
  }
  #pragma unroll
  for (int mi = 0; mi < 4; mi++) {
    #pragma unroll
    for (int r = 0; r < 4; r++) {
      const int orow = mt * 128 + wm + mi * 16 + quad * 4 + r;
      const float iv = invv[orow], sh = shv[orow];
      #pragma unroll
      for (int ni = 0; ni < 4; ni++) {
        const int n = nt * 128 + wn + ni * 16 + l16;
        dout[((size_t)(z * NC + orow)) * NN + n] = acc[mi][ni][r] * iv + sh;
      }
    }
  }
}

// ---------- launch ----------
extern "C" void kernel_launch(void* const* d_in, const int* in_sizes, int n_in,
                              void* d_out, int out_size, void* d_ws, size_t ws_size,
                              hipStream_t stream) {
  (void)in_sizes; (void)n_in; (void)out_size; (void)ws_size;
  const float* x  = (const float*)d_in[0];
  const float* wq = (const float*)d_in[1];
  const float* wk = (const float*)d_in[2];
  const float* wv = (const float*)d_in[3];
  const float* wp = (const float*)d_in[4];
  const float* bp = (const float*)d_in[5];
  const float* qg = (const float*)d_in[6],  *qb = (const float*)d_in[7];
  const float* qm = (const float*)d_in[8],  *qva = (const float*)d_in[9];
  const float* kg = (const float*)d_in[10], *kb = (const float*)d_in[11];
  const float* km = (const float*)d_in[12], *kva = (const float*)d_in[13];
  const float* vg = (const float*)d_in[14], *vb = (const float*)d_in[15];
  const float* vm = (const float*)d_in[16], *vva = (const float*)d_in[17];
  const float* pg = (const float*)d_in[18], *pb = (const float*)d_in[19];
  const float* pm = (const float*)d_in[20], *pva = (const float*)d_in[21];

  float* out = (float*)d_out;       // outputs in return order
  float* xs  = out + NE1;
  float* dq  = out + 2 * NE1;
  float* dk  = out + 3 * NE1;
  float* dv  = out + 4 * NE1;

  char* ws = (char*)d_ws;
  unsigned short* xbits = (unsigned short*)ws;                  // 4194304 B
  unsigned short* Wqkv  = (unsigned short*)(ws + 4194304);      // 1179648 B
  unsigned short* Wp    = (unsigned short*)(ws + 5373952);      // 393216 B
  float* kvout          = (float*)(ws + 5767168);               // 1048576 B
  unsigned short* qbits = (unsigned short*)(ws + 6815744);      // 4194304 B
  unsigned short* kbits = (unsigned short*)(ws + 11010048);     // 4194304 B
  unsigned short* vbits = (unsigned short*)(ws + 15204352);     // 4194304 B
  unsigned short* sbits = (unsigned short*)(ws + 19398656);     // 4194304 B
  float* invqkv         = (float*)(ws + 23592960);              // 768 floats
  float* shqkv          = invqkv + 768;
  float* invp           = shqkv + 768;
  float* shp            = invp + 256;

  prep_kernel<<<1028, 256, 0, stream>>>(wq, wk, wv, wp, bp,
                                        qg, qb, qm, qva, kg, kb, km, kva,
                                        vg, vb, vm, vva, pg, pb, pm, pva,
                                        Wqkv, Wp, invqkv, shqkv, invp, shp);
  lifx_kernel<<<dim3(64, 4, 16), 256, 0, stream>>>(x, xs, xbits);
  qkv_gemm<<<dim3(64, 6, 16), 256, 0, stream>>>(xbits, Wqkv, invqkv, shqkv,
                                                dq, dk, dv, qbits, kbits, vbits);
  kv_kernel<<<dim3(8, 32), 256, 0, stream>>>((const unsigned long long*)kbits,
                                             (const unsigned long long*)vbits, kvout);
  attn_kernel<<<dim3(16, 8, 16), 256, 0, stream>>>(qbits, kvout, sbits);
  p_gemm<<<dim3(32, 2, 32), 256, 0, stream>>>(sbits, Wp, invp, shp, out);
}